// Round 14
// baseline (914.571 us; speedup 1.0000x reference)
//
#include <hip/hip_runtime.h>
#include <stdint.h>

// LSTM B=256,T=2048,D=U=64 fp32. Grid 256 WGs x 64 thr = ONE WAVE per batch.
// R13 (586us) paid a cross-wave s_barrier + skew every step (~280cyc of 686).
// R14: whole recurrence in one wave -> LDS ops are program-ordered within a
// wave -> ZERO barriers / ZERO s_waitcnt asm in the t-loop.
//  - Bh[16][2] f16x8 in registers (128 VGPR). Bx in LDS (4KB), read per
//    chunk only (R11's 256-VGPR blowup fixed).
//  - replicated-A (all 16 rows = h, R13-proven): z for every col lands in
//    every lane; lane (g,j) statically owns unit u=g*16+j (c never moves).
//  - z extraction: pick4 cndmask over h_T[0], T = 4q+g (static reg indices).
//  - per-step: 4x ds_read_b32 xz + 2x ds_read_b128 A + 32 MFMA (zero-C,
//    2-deep) + 25 VALU state + 1x ds_write_b16 h + 2 coalesced stores.
//  - xz per 16-step chunk: MFMA rows=timesteps, scattered b32 to
//    sXZ[s][q][u]; bias folded as scalar at state time (no acc init).
// k-map f(g,e)=g*8+e on BOTH A and B; C/D layout m89 (col=lane&15,
// row=4*(lane>>4)+reg) - verified R9/R10/R13.

#define T_STEPS 2048
#define DIM     64
#define GATES   256
#define CHUNK   16
#define NCHUNK  (T_STEPS / CHUNK)

typedef _Float16 f16;
typedef _Float16 f16x8 __attribute__((ext_vector_type(8)));
typedef float    f32x4 __attribute__((ext_vector_type(4)));

__device__ __forceinline__ float sigm(float z) {
    return __builtin_amdgcn_rcpf(1.f + __expf(-z));
}

#define MFMA16(A, B, C) __builtin_amdgcn_mfma_f32_16x16x32_f16(A, B, C, 0, 0, 0)

__device__ __forceinline__ void pack8(f16x8& d, const float4& a, const float4& b) {
    d[0]=(f16)a.x; d[1]=(f16)a.y; d[2]=(f16)a.z; d[3]=(f16)a.w;
    d[4]=(f16)b.x; d[5]=(f16)b.y; d[6]=(f16)b.z; d[7]=(f16)b.w;
}

// select A[m] from {A0..A3} with uniform-per-lane m (cndmask tree)
__device__ __forceinline__ float pick4(int m, float A0, float A1, float A2, float A3) {
    float r  = (m & 1) ? A1 : A0;
    float sx = (m & 1) ? A3 : A2;
    return (m & 2) ? sx : r;
}

__global__ __attribute__((amdgpu_flat_work_group_size(64, 64),
                          amdgpu_waves_per_eu(1, 1)))
void lstm_r14_kernel(const float* __restrict__ x,
                     const float* __restrict__ Wx,
                     const float* __restrict__ Wh,
                     const float* __restrict__ bias,
                     float* __restrict__ out)
{
    __shared__ __align__(16) f16   sH[2][64];            // h dbuf
    __shared__ __align__(16) f16x8 sBx[CHUNK][2][64];    // Bx frags, 4KB
    __shared__ __align__(16) float sXZ[CHUNK][4][64];    // xz[s][q][u], 16KB

    const int l = threadIdx.x;       // 0..63
    const int j = l & 15;            // col-in-tile / A-row (xz MFMA)
    const int g = l >> 4;            // k-group; owns unit u = g*16+j
    const int u = g * 16 + j;

    const int batch = blockIdx.x;
    const float* xb = x + (size_t)batch * T_STEPS * DIM;
    float* ob = out + (size_t)batch * T_STEPS * (2 * DIM);

    // ---- Bh[16][2] in registers; Bx staged to LDS. tile T: cols 16T+j ----
    f16x8 Bh[16][2];
#pragma unroll
    for (int T = 0; T < 16; ++T) {
        const int col = 16 * T + j;
#pragma unroll
        for (int ks = 0; ks < 2; ++ks) {
            f16x8 bx, bh;
#pragma unroll
            for (int e = 0; e < 8; ++e) {
                const int k = ks * 32 + g * 8 + e;
                bh[e] = (f16)Wh[k * GATES + col];
                bx[e] = (f16)Wx[k * GATES + col];
            }
            Bh[T][ks] = bh;
            sBx[T][ks][l] = bx;
        }
    }
    // bias for this lane's unit, 4 gates
    const float bi = bias[u], bf = bias[64 + u], bg = bias[128 + u], bo = bias[192 + u];

    sH[0][l] = (f16)0.f;
    sH[1][l] = (f16)0.f;

    const f32x4 zero4 = {0.f, 0.f, 0.f, 0.f};

    // ---- x prefetch chunk 0: A row = ts = j, feats g*8.. ----
    float4 x0, x1, x2, x3;
    {
        const float* xr = xb + (size_t)j * DIM + g * 8;
        x0 = *(const float4*)(xr);      x1 = *(const float4*)(xr + 4);
        x2 = *(const float4*)(xr + 32); x3 = *(const float4*)(xr + 36);
    }

    float c = 0.f;                    // this lane's unit, never migrates

#pragma unroll 1
    for (int n = 0; n < NCHUNK; ++n) {
        // ---- xz chunk: X_chunk @ Wx (rows = 16 ts), zero-C ----
        f16x8 ax0, ax1;
        pack8(ax0, x0, x1); pack8(ax1, x2, x3);
#pragma unroll
        for (int T = 0; T < 16; ++T) {
            f32x4 a = MFMA16(ax0, sBx[T][0][l], zero4);
            a = MFMA16(ax1, sBx[T][1][l], a);
            // scatter: value r -> ts=4g+r, col=16T+j -> [s][T>>2][(T&3)*16+j]
#pragma unroll
            for (int r = 0; r < 4; ++r)
                sXZ[4 * g + r][T >> 2][(T & 3) * 16 + j] = a[r];
        }

        // prefetch next chunk's x (16-step window hides the HBM latency)
        if (n + 1 < NCHUNK) {
            const float* xr = xb + ((size_t)(n + 1) * CHUNK + j) * DIM + g * 8;
            x0 = *(const float4*)(xr);      x1 = *(const float4*)(xr + 4);
            x2 = *(const float4*)(xr + 32); x3 = *(const float4*)(xr + 36);
        }

#pragma unroll
        for (int s = 0; s < CHUNK; ++s) {
            const int pb = s & 1;
            // xz for this lane's unit (4 conflict-free b32 reads)
            float xzi = sXZ[s][0][u], xzf = sXZ[s][1][u];
            float xzg = sXZ[s][2][u], xzo = sXZ[s][3][u];
            // A = h replicated in all rows (read depends only on g)
            f16x8 A0 = *(const f16x8*)&sH[pb][g * 8];
            f16x8 A1 = *(const f16x8*)&sH[pb][32 + g * 8];

            // h @ Wh for all 16 tiles, zero-C, 2-deep
            f32x4 hv[16];
#pragma unroll
            for (int T = 0; T < 16; ++T) {
                f32x4 a = MFMA16(A0, Bh[T][0], zero4);
                hv[T] = MFMA16(A1, Bh[T][1], a);
            }
            // z_q = hv[4q+g][0] + xz_q + bias_q (static reg indices via pick4)
            float zi = pick4(g, hv[0][0],  hv[1][0],  hv[2][0],  hv[3][0])  + xzi + bi;
            float zf = pick4(g, hv[4][0],  hv[5][0],  hv[6][0],  hv[7][0])  + xzf + bf;
            float zg = pick4(g, hv[8][0],  hv[9][0],  hv[10][0], hv[11][0]) + xzg + bg;
            float zo = pick4(g, hv[12][0], hv[13][0], hv[14][0], hv[15][0]) + xzo + bo;

            float gi = sigm(zi), gf = sigm(zf), go = sigm(zo);
            float gg = fmaf(2.f, sigm(zg + zg), -1.f);
            c = fmaf(gf, c, gi * gg);
            float e2 = __expf(-2.f * fabsf(c));
            float th = copysignf(
                fmaf(-2.f, e2 * __builtin_amdgcn_rcpf(1.f + e2), 1.f), c);
            float hh = go * th;

            sH[pb ^ 1][u] = (f16)hh;          // full-wave b16, program-ordered
            const size_t t = (size_t)n * CHUNK + s;
            ob[t * 128 + u]      = c;         // coalesced 64-lane store
            ob[t * 128 + 64 + u] = hh;        // coalesced 64-lane store
        }
    }
}

extern "C" void kernel_launch(void* const* d_in, const int* in_sizes, int n_in,
                              void* d_out, int out_size, void* d_ws, size_t ws_size,
                              hipStream_t stream) {
    const float* x  = (const float*)d_in[0];
    const float* Wx = (const float*)d_in[1];
    const float* Wh = (const float*)d_in[2];
    const float* b  = (const float*)d_in[3];
    float* out = (float*)d_out;

    hipLaunchKernelGGL(lstm_r14_kernel, dim3(256), dim3(64), 0, stream,
                       x, Wx, Wh, b, out);
}

// Round 15
// 576.301 us; speedup vs baseline: 1.5870x; 1.5870x over previous
//
#include <hip/hip_runtime.h>
#include <stdint.h>

// LSTM B=256,T=2048,D=U=64 fp32. 256 WGs (1 batch) x 256 thr (4 waves).
// R15 = R13 (586us, best) + surgical critical-path reordering:
//  - xz[s+1] prefetched PRE-barrier into a rotating register (sXZ is
//    wave-private + stable all chunk) -> post-barrier LDS burst is A-reads
//    only (8 b128 across 4 waves instead of 12).
//  - chunk-start lgkmcnt(0) drain removed: DS ops are program-ordered
//    within a wave, so the s=0 xz read after the scatter is consistent.
//  - A-reads are the first instructions after the barrier.
//  - per-chunk output base pointer (no per-step 64-bit mul).
// Structure otherwise identical to R13 (replay-proven): replicated-A h-MFMA
// with persistent zero-C, xz per chunk via MFMA rows=timesteps, one
// lgkm-only barrier per step, vmcnt never drained.
// k-map f(g,e)=g*8+e on BOTH A and B; C/D layout m89-verified.

#define T_STEPS 2048
#define DIM     64
#define GATES   256
#define CHUNK   16
#define NCHUNK  (T_STEPS / CHUNK)

typedef _Float16 f16;
typedef _Float16 f16x8 __attribute__((ext_vector_type(8)));
typedef float    f32x4 __attribute__((ext_vector_type(4)));

__device__ __forceinline__ void sync_lds() {
    __builtin_amdgcn_sched_barrier(0);
    asm volatile("s_waitcnt lgkmcnt(0)" ::: "memory");
    __builtin_amdgcn_sched_barrier(0);
    __builtin_amdgcn_s_barrier();
    __builtin_amdgcn_sched_barrier(0);
}

__device__ __forceinline__ float sigm(float z) {
    return __builtin_amdgcn_rcpf(1.f + __expf(-z));
}

#define MFMA16(A, B, C) __builtin_amdgcn_mfma_f32_16x16x32_f16(A, B, C, 0, 0, 0)

__device__ __forceinline__ void pack8(f16x8& d, const float4& a, const float4& b) {
    d[0]=(f16)a.x; d[1]=(f16)a.y; d[2]=(f16)a.z; d[3]=(f16)a.w;
    d[4]=(f16)b.x; d[5]=(f16)b.y; d[6]=(f16)b.z; d[7]=(f16)b.w;
}

__global__ __launch_bounds__(256, 1)
void lstm_r15_kernel(const float* __restrict__ x,
                     const float* __restrict__ Wx,
                     const float* __restrict__ Wh,
                     const float* __restrict__ bias,
                     float* __restrict__ out)
{
    __shared__ __align__(16) f16   sH[2][64];             // h dbuf (f16)
    __shared__ __align__(16) float sXZ[4][CHUNK][16][4];  // wave-private xz

    const int tid  = threadIdx.x;
    const int lane = tid & 63;
    const int w    = tid >> 6;       // wave 0..3 -> units w*16..+16
    const int j    = lane & 15;      // col-in-tile (B,D) / row (A, xz MFMA)
    const int g    = lane >> 4;      // k-group: k = ks*32 + g*8 + e
    const int u    = w * 16 + j;     // unit

    const int batch = blockIdx.x;
    const float* xb = x + (size_t)batch * T_STEPS * DIM;
    float* ob = out + (size_t)batch * T_STEPS * (2 * DIM);

    // ---- persistent B fragments: col = q*64 + u, k = ks*32 + g*8 + e ----
    f16x8 Bh[4][2], Bx[4][2];
    f32x4 bias4[4];
#pragma unroll
    for (int q = 0; q < 4; ++q) {
        const int col = q * 64 + u;
        const float bb = bias[col];
        bias4[q][0] = bb; bias4[q][1] = bb; bias4[q][2] = bb; bias4[q][3] = bb;
#pragma unroll
        for (int ks = 0; ks < 2; ++ks)
#pragma unroll
            for (int e = 0; e < 8; ++e) {
                const int k = ks * 32 + g * 8 + e;
                Bh[q][ks][e] = (f16)Wh[k * GATES + col];
                Bx[q][ks][e] = (f16)Wx[k * GATES + col];
            }
    }
    const f32x4 zero4 = {0.f, 0.f, 0.f, 0.f};

    if (tid < 128) sH[tid >> 6][tid & 63] = (f16)0.f;

    // ---- prefetch x chunk 0: A row = ts = j, feats g*8.. ----
    float4 x0, x1, x2, x3;
    {
        const float* xr = xb + (size_t)j * DIM + g * 8;
        x0 = *(const float4*)(xr);      x1 = *(const float4*)(xr + 4);
        x2 = *(const float4*)(xr + 32); x3 = *(const float4*)(xr + 36);
    }

    float c = 0.f;   // replicated: every lane-group's lane j holds c[u]
    __syncthreads();

#pragma unroll 1
    for (int n = 0; n < NCHUNK; ++n) {
        // ---- xz chunk: z[q] = bias + X_chunk @ Wx (rows = 16 ts) ----
        f16x8 ax0, ax1;
        pack8(ax0, x0, x1); pack8(ax1, x2, x3);
        f32x4 z0 = MFMA16(ax0, Bx[0][0], bias4[0]); z0 = MFMA16(ax1, Bx[0][1], z0);
        f32x4 z1 = MFMA16(ax0, Bx[1][0], bias4[1]); z1 = MFMA16(ax1, Bx[1][1], z1);
        f32x4 z2 = MFMA16(ax0, Bx[2][0], bias4[2]); z2 = MFMA16(ax1, Bx[2][1], z2);
        f32x4 z3 = MFMA16(ax0, Bx[3][0], bias4[3]); z3 = MFMA16(ax1, Bx[3][1], z3);
        // scatter to wave-private sXZ: row = 4g+r (D-layout), unit j
#pragma unroll
        for (int r = 0; r < 4; ++r) {
            float4 v = {z0[r], z1[r], z2[r], z3[r]};
            *(float4*)&sXZ[w][4 * g + r][j][0] = v;
        }
        // s=0 xz read: DS in-wave program order makes this consistent with
        // the scatter above — no lgkm drain needed.
        float4 xzv = *(const float4*)&sXZ[w][0][j][0];

        // prefetch next chunk's x (returns during the 16 steps below)
        if (n + 1 < NCHUNK) {
            const float* xr = xb + ((size_t)(n + 1) * CHUNK + j) * DIM + g * 8;
            x0 = *(const float4*)(xr);      x1 = *(const float4*)(xr + 4);
            x2 = *(const float4*)(xr + 32); x3 = *(const float4*)(xr + 36);
        }

        float* obn = ob + (size_t)n * CHUNK * 128;

#pragma unroll
        for (int s = 0; s < CHUNK; ++s) {
            const int pb = s & 1;
            // A-reads FIRST post-barrier (the only LDS on the critical path)
            f16x8 A0 = *(const f16x8*)&sH[pb][g * 8];
            f16x8 A1 = *(const f16x8*)&sH[pb][32 + g * 8];

            f32x4 h0 = MFMA16(A0, Bh[0][0], zero4); h0 = MFMA16(A1, Bh[0][1], h0);
            f32x4 h1 = MFMA16(A0, Bh[1][0], zero4); h1 = MFMA16(A1, Bh[1][1], h1);
            f32x4 h2 = MFMA16(A0, Bh[2][0], zero4); h2 = MFMA16(A1, Bh[2][1], h2);
            f32x4 h3 = MFMA16(A0, Bh[3][0], zero4); h3 = MFMA16(A1, Bh[3][1], h3);

            float zi = h0[0] + xzv.x, zf = h1[0] + xzv.y;
            float zg = h2[0] + xzv.z, zo = h3[0] + xzv.w;
            float gi = sigm(zi), gf = sigm(zf), go = sigm(zo);
            float gg = fmaf(2.f, sigm(zg + zg), -1.f);
            c = fmaf(gf, c, gi * gg);
            float e2 = __expf(-2.f * fabsf(c));
            float th = copysignf(
                fmaf(-2.f, e2 * __builtin_amdgcn_rcpf(1.f + e2), 1.f), c);
            float hh = go * th;

            // next step's xz prefetch — pre-barrier, off the post-barrier
            // burst (wave-private, stable; s=15's read is dead/discarded)
            float4 xzn = *(const float4*)&sXZ[w][(s + 1) & 15][j][0];

            if (g == 2)      sH[pb ^ 1][u] = (f16)hh;     // next-step h
            else if (g == 0) obn[s * 128 + u]      = c;   // cell out
            else if (g == 1) obn[s * 128 + 64 + u] = hh;  // hidden out
            sync_lds();
            xzv = xzn;
        }
    }
}

extern "C" void kernel_launch(void* const* d_in, const int* in_sizes, int n_in,
                              void* d_out, int out_size, void* d_ws, size_t ws_size,
                              hipStream_t stream) {
    const float* x  = (const float*)d_in[0];
    const float* Wx = (const float*)d_in[1];
    const float* Wh = (const float*)d_in[2];
    const float* b  = (const float*)d_in[3];
    float* out = (float*)d_out;

    hipLaunchKernelGGL(lstm_r15_kernel, dim3(256), dim3(256), 0, stream,
                       x, Wx, Wh, b, out);
}